// Round 1
// baseline (556.860 us; speedup 1.0000x reference)
//
#include <hip/hip_runtime.h>

// CrossAttentionSequencePool — fp32 correctness-first baseline.
// Pipeline:
//  1. chunkmax:   per-chunk (64-row) column max of key            [512,256]
//  2. chunkscan:  exclusive prefix/suffix max across chunks       [512,256] x2
//  3. scanwrite:  materialize x_before / x_after                  [32768,256] x2
//  4. gemm_nt<relu>: h1 = relu([key|bef|aft] @ k1_w^T + k1_b)     K=768
//  5. gemm_nt:       x_key = h1 @ k2_w^T + k2_b
//  6. gemm_nt<relu>: hq1 = relu(query @ q1_w^T + q1_b)
//  7. gemm_nt:       x_query = hq1 @ q2_w^T + q2_b
//  8. gemm_nt:       out = (x_query @ x_key^T) * 0.0625
// All GEMMs are NT (row-major A [M,K], row-major B [N,K]) — coalesced both sides.

#define NK 32768
#define DIM 256
#define MQ 1024
#define CHUNK 64
#define NCHUNK (NK / CHUNK) // 512

#define TM 64
#define TN 64
#define TK 16
#define LDSP 68 // padded LDS stride: 68*4B = 272B, 16B-aligned rows, breaks pow2 banks

__global__ __launch_bounds__(256) void chunkmax_kernel(const float* __restrict__ key,
                                                       float* __restrict__ cmax) {
    int col = threadIdx.x;
    int c = blockIdx.x;
    const float* p = key + (size_t)c * CHUNK * DIM + col;
    float m = -INFINITY;
#pragma unroll 8
    for (int r = 0; r < CHUNK; ++r) m = fmaxf(m, p[(size_t)r * DIM]);
    cmax[c * DIM + col] = m;
}

__global__ __launch_bounds__(256) void chunkscan_kernel(const float* __restrict__ cmax,
                                                        float* __restrict__ cbef,
                                                        float* __restrict__ caft) {
    int col = threadIdx.x;
    float run = -INFINITY;
    for (int c = 0; c < NCHUNK; ++c) {
        cbef[c * DIM + col] = run;
        run = fmaxf(run, cmax[c * DIM + col]);
    }
    run = -INFINITY;
    for (int c = NCHUNK - 1; c >= 0; --c) {
        caft[c * DIM + col] = run;
        run = fmaxf(run, cmax[c * DIM + col]);
    }
}

__global__ __launch_bounds__(256) void scanwrite_kernel(const float* __restrict__ key,
                                                        const float* __restrict__ cbef,
                                                        const float* __restrict__ caft,
                                                        float* __restrict__ xbef,
                                                        float* __restrict__ xaft) {
    int col = threadIdx.x;
    int c = blockIdx.x;
    size_t base = (size_t)c * CHUNK * DIM + col;
    float run = cbef[c * DIM + col]; // -inf for c==0
    for (int r = 0; r < CHUNK; ++r) {
        int gr = c * CHUNK + r;
        size_t idx = base + (size_t)r * DIM;
        xbef[idx] = (gr == 0) ? 0.0f : run; // exclusive, zero boundary at row 0
        run = fmaxf(run, key[idx]);
    }
    run = caft[c * DIM + col]; // -inf for last chunk
    for (int r = CHUNK - 1; r >= 0; --r) {
        int gr = c * CHUNK + r;
        size_t idx = base + (size_t)r * DIM;
        xaft[idx] = (gr == NK - 1) ? 0.0f : run; // zero boundary at last row
        run = fmaxf(run, key[idx]);
    }
}

// C[m][n] = act( sum_k A[m][k] * B[n][k] + bias[n] ) * scale
// A is a virtual concat of up to 3 row-major [M,256] parts along k (for K=768).
// B row-major [N, ldb]. All dims multiples of tile sizes (64/64/16).
template <bool RELU>
__global__ __launch_bounds__(256) void gemm_nt(const float* __restrict__ A0,
                                               const float* __restrict__ A1,
                                               const float* __restrict__ A2,
                                               const float* __restrict__ B,
                                               const float* __restrict__ bias,
                                               float* __restrict__ C,
                                               int M, int N, int K, int ldb, float scale) {
    __shared__ float As[TK][LDSP];
    __shared__ float Bs[TK][LDSP];
    int tid = threadIdx.x;
    int tx = tid & 15, ty = tid >> 4;
    int m0 = blockIdx.y * TM, n0 = blockIdx.x * TN;
    int lr = tid >> 2;      // 0..63 tile row
    int lc = (tid & 3) * 4; // 0,4,8,12 tile col (float4)
    float acc[4][4] = {};
    for (int k0 = 0; k0 < K; k0 += TK) {
        int k = k0 + lc;
        // k-tiles never straddle a 256 boundary (16 | 256), so part choice is tile-uniform
        const float* Ap = (k < 256) ? A0 : (k < 512 ? A1 : A2);
        float4 va = *reinterpret_cast<const float4*>(Ap + (size_t)(m0 + lr) * DIM + (k & 255));
        float4 vb = *reinterpret_cast<const float4*>(B + (size_t)(n0 + lr) * ldb + k0 + lc);
        As[lc + 0][lr] = va.x;
        As[lc + 1][lr] = va.y;
        As[lc + 2][lr] = va.z;
        As[lc + 3][lr] = va.w;
        Bs[lc + 0][lr] = vb.x;
        Bs[lc + 1][lr] = vb.y;
        Bs[lc + 2][lr] = vb.z;
        Bs[lc + 3][lr] = vb.w;
        __syncthreads();
#pragma unroll
        for (int kk = 0; kk < TK; ++kk) {
            float a[4], b[4];
#pragma unroll
            for (int i = 0; i < 4; ++i) a[i] = As[kk][ty * 4 + i];
#pragma unroll
            for (int j = 0; j < 4; ++j) b[j] = Bs[kk][tx * 4 + j];
#pragma unroll
            for (int i = 0; i < 4; ++i)
#pragma unroll
                for (int j = 0; j < 4; ++j) acc[i][j] += a[i] * b[j];
        }
        __syncthreads();
    }
    float bv[4] = {0.f, 0.f, 0.f, 0.f};
    if (bias) {
#pragma unroll
        for (int j = 0; j < 4; ++j) bv[j] = bias[n0 + tx * 4 + j];
    }
#pragma unroll
    for (int i = 0; i < 4; ++i) {
        float r[4];
#pragma unroll
        for (int j = 0; j < 4; ++j) {
            float v = acc[i][j] + bv[j];
            if (RELU) v = fmaxf(v, 0.0f);
            r[j] = v * scale;
        }
        float4 v4 = {r[0], r[1], r[2], r[3]};
        *reinterpret_cast<float4*>(C + (size_t)(m0 + ty * 4 + i) * N + n0 + tx * 4) = v4;
    }
}

extern "C" void kernel_launch(void* const* d_in, const int* in_sizes, int n_in,
                              void* d_out, int out_size, void* d_ws, size_t ws_size,
                              hipStream_t stream) {
    const float* query = (const float*)d_in[0]; // [1024,256]
    const float* key   = (const float*)d_in[1]; // [32768,256]
    const float* q1_w  = (const float*)d_in[2]; // [256,256]
    const float* q1_b  = (const float*)d_in[3];
    const float* q2_w  = (const float*)d_in[4]; // [256,256]
    const float* q2_b  = (const float*)d_in[5];
    const float* k1_w  = (const float*)d_in[6]; // [256,768]
    const float* k1_b  = (const float*)d_in[7];
    const float* k2_w  = (const float*)d_in[8]; // [256,256]
    const float* k2_b  = (const float*)d_in[9];
    float* out = (float*)d_out; // [1024, 32768]

    char* ws = (char*)d_ws;
    const size_t SZ = (size_t)NK * DIM * sizeof(float); // 33,554,432
    float* x_before = (float*)(ws);
    float* x_after  = (float*)(ws + SZ);
    float* h1       = (float*)(ws + 2 * SZ);
    float* x_key    = (float*)(ws + 3 * SZ);
    // chunk buffers overlay h1's region (consumed before h1 is written)
    float* cmax = h1;
    float* cbef = h1 + NCHUNK * DIM;
    float* caft = h1 + 2 * NCHUNK * DIM;
    // query-path buffers overlay x_before's region (consumed by the time these run)
    float* hq1     = (float*)(ws);
    float* x_query = (float*)(ws + (size_t)MQ * DIM * sizeof(float));

    // 1-3: exclusive prefix/suffix column max of key
    chunkmax_kernel<<<NCHUNK, 256, 0, stream>>>(key, cmax);
    chunkscan_kernel<<<1, 256, 0, stream>>>(cmax, cbef, caft);
    scanwrite_kernel<<<NCHUNK, 256, 0, stream>>>(key, cbef, caft, x_before, x_after);

    // 4: h1 = relu([key|bef|aft] @ k1_w^T + k1_b)   M=32768 N=256 K=768
    gemm_nt<true><<<dim3(DIM / TN, NK / TM), 256, 0, stream>>>(
        key, x_before, x_after, k1_w, k1_b, h1, NK, DIM, 3 * DIM, 3 * DIM, 1.0f);
    // 5: x_key = h1 @ k2_w^T + k2_b                 M=32768 N=256 K=256
    gemm_nt<false><<<dim3(DIM / TN, NK / TM), 256, 0, stream>>>(
        h1, h1, h1, k2_w, k2_b, x_key, NK, DIM, DIM, DIM, 1.0f);
    // 6: hq1 = relu(query @ q1_w^T + q1_b)          M=1024 N=256 K=256
    gemm_nt<true><<<dim3(DIM / TN, MQ / TM), 256, 0, stream>>>(
        query, query, query, q1_w, q1_b, hq1, MQ, DIM, DIM, DIM, 1.0f);
    // 7: x_query = hq1 @ q2_w^T + q2_b
    gemm_nt<false><<<dim3(DIM / TN, MQ / TM), 256, 0, stream>>>(
        hq1, hq1, hq1, q2_w, q2_b, x_query, MQ, DIM, DIM, DIM, 1.0f);
    // 8: out = (x_query @ x_key^T) / 16             M=1024 N=32768 K=256
    gemm_nt<false><<<dim3(NK / TN, MQ / TM), 256, 0, stream>>>(
        x_query, x_query, x_query, x_key, nullptr, out, MQ, NK, DIM, DIM, 0.0625f);
}

// Round 2
// 262.066 us; speedup vs baseline: 2.1249x; 2.1249x over previous
//
#include <hip/hip_runtime.h>
#include <hip/hip_bf16.h>

// CrossAttentionSequencePool — split-bf16 MFMA pipeline.
//  scan (fp32) -> xcat hi/lo bf16 [32768,768]
//  gemm_bs<relu,split>: h1 = relu(xcat @ k1_w^T + b)        (h1 pair lives in d_out)
//  gemm_bs<.,split>:    x_key = h1 @ k2_w^T + b             (overlays dead xcat region)
//  query path same, then final: out = (x_query @ x_key^T)/16  fp32 into d_out.
// Each GEMM: C = A*B^T with A=Ah+Al, B=Bh+Bl (bf16), 3 MFMA products into fp32 acc.

#define NK 32768
#define DIM 256
#define MQ 1024
#define CHUNK 64
#define NCHUNK (NK / CHUNK)

typedef __hip_bfloat16 bf16;
typedef short bf16x8 __attribute__((ext_vector_type(8)));
typedef float f32x4 __attribute__((ext_vector_type(4)));

__device__ __forceinline__ void gload16(const void* g, void* l) {
    __builtin_amdgcn_global_load_lds(
        (const __attribute__((address_space(1))) unsigned int*)g,
        (__attribute__((address_space(3))) unsigned int*)l, 16, 0, 0);
}

__device__ __forceinline__ void split2(float v, bf16* ph, bf16* pl, size_t idx) {
    bf16 h = __float2bfloat16(v);
    ph[idx] = h;
    pl[idx] = __float2bfloat16(v - __bfloat162float(h));
}

// ---------------- scan ----------------
__global__ __launch_bounds__(256) void chunkmax_kernel(const float* __restrict__ key,
                                                       float* __restrict__ cmax) {
    int col = threadIdx.x, c = blockIdx.x;
    const float* p = key + (size_t)c * CHUNK * DIM + col;
    float m = -INFINITY;
#pragma unroll 8
    for (int r = 0; r < CHUNK; ++r) m = fmaxf(m, p[(size_t)r * DIM]);
    cmax[c * DIM + col] = m;
}

__global__ __launch_bounds__(256) void chunkscan_kernel(const float* __restrict__ cmax,
                                                        float* __restrict__ cbef,
                                                        float* __restrict__ caft) {
    int col = threadIdx.x;
    float run = -INFINITY;
    for (int c = 0; c < NCHUNK; ++c) {
        cbef[c * DIM + col] = run;
        run = fmaxf(run, cmax[c * DIM + col]);
    }
    run = -INFINITY;
    for (int c = NCHUNK - 1; c >= 0; --c) {
        caft[c * DIM + col] = run;
        run = fmaxf(run, cmax[c * DIM + col]);
    }
}

// writes xcat hi/lo: row r -> [key | x_before | x_after] as bf16 pairs
__global__ __launch_bounds__(256) void scanwrite_kernel(const float* __restrict__ key,
                                                        const float* __restrict__ cbef,
                                                        const float* __restrict__ caft,
                                                        bf16* __restrict__ xh,
                                                        bf16* __restrict__ xl) {
    __shared__ float sk[CHUNK][DIM];
    int col = threadIdx.x, c = blockIdx.x;
    float run = cbef[c * DIM + col]; // -inf for c==0
    for (int r = 0; r < CHUNK; ++r) {
        int gr = c * CHUNK + r;
        float kv = key[(size_t)gr * DIM + col];
        sk[r][col] = kv;
        size_t base = (size_t)gr * (3 * DIM) + col;
        split2(kv, xh, xl, base);
        float bv = (gr == 0) ? 0.0f : run;
        split2(bv, xh, xl, base + DIM);
        run = fmaxf(run, kv);
    }
    run = caft[c * DIM + col]; // -inf for last chunk
    for (int r = CHUNK - 1; r >= 0; --r) {
        int gr = c * CHUNK + r;
        float kv = sk[r][col];
        size_t base = (size_t)gr * (3 * DIM) + col;
        float av = (gr == NK - 1) ? 0.0f : run;
        split2(av, xh, xl, base + 2 * DIM);
        run = fmaxf(run, kv);
    }
}

// ---------------- converts (weights + query) ----------------
__global__ __launch_bounds__(256) void convert_kernel(
    const float* __restrict__ q, const float* __restrict__ q1w, const float* __restrict__ q2w,
    const float* __restrict__ k1w, const float* __restrict__ k2w,
    bf16* qh, bf16* ql, bf16* q1h, bf16* q1l, bf16* q2h, bf16* q2l,
    bf16* k1h, bf16* k1l, bf16* k2h, bf16* k2l) {
    int i = blockIdx.x * 256 + threadIdx.x;
    const float* src; bf16 *dh, *dl; int off;
    if (i < 262144)      { src = q;   dh = qh;  dl = ql;  off = i; }
    else if (i < 327680) { src = q1w; dh = q1h; dl = q1l; off = i - 262144; }
    else if (i < 393216) { src = q2w; dh = q2h; dl = q2l; off = i - 327680; }
    else if (i < 589824) { src = k1w; dh = k1h; dl = k1l; off = i - 393216; }
    else                 { src = k2w; dh = k2h; dl = k2l; off = i - 589824; }
    float v = src[off];
    bf16 h = __float2bfloat16(v);
    dh[off] = h;
    dl[off] = __float2bfloat16(v - __bfloat162float(h));
}

// ---------------- split-bf16 MFMA GEMM (NT) ----------------
// C[m][n] = act(sum_k A[m][k]*B[n][k] + bias[n]) * scale
// BM=BN=128, BK=32, 4 waves (2x2), each wave 64x64 = 4x4 frags of 16x16x32.
template <bool RELU, bool SPLIT>
__global__ __launch_bounds__(256) void gemm_bs(
    const bf16* __restrict__ Ah, const bf16* __restrict__ Al,
    const bf16* __restrict__ Bh, const bf16* __restrict__ Bl,
    const float* __restrict__ bias,
    float* __restrict__ Cf, bf16* __restrict__ Ch, bf16* __restrict__ Cl,
    int M, int N, int K, float scale) {
    __shared__ __align__(16) bf16 sAh[128 * 32], sAl[128 * 32];
    __shared__ __align__(16) bf16 sBh[128 * 32], sBl[128 * 32];
    const int t = threadIdx.x;
    const int lane = t & 63, wid = t >> 6;
    const int m0 = blockIdx.y * 128, n0 = blockIdx.x * 128;
    const int wr = wid >> 1, wc = wid & 1;
    const int l15 = lane & 15, l4 = lane >> 4;

    f32x4 acc[4][4];
#pragma unroll
    for (int i = 0; i < 4; ++i)
#pragma unroll
        for (int j = 0; j < 4; ++j) {
            acc[i][j][0] = 0.f; acc[i][j][1] = 0.f; acc[i][j][2] = 0.f; acc[i][j][3] = 0.f;
        }

    // staging: tile = 512 x 16B atoms; atom a: row=a>>2, elems (a&3)*8; thread t owns atoms t and t+256.
    const int arow = t >> 2;
    const int acol = (t & 3) * 8;
    const unsigned lo0 = (unsigned)(wid * 1024);
    const unsigned lo1 = (unsigned)(4096 + wid * 1024);

    for (int k0 = 0; k0 < K; k0 += 32) {
        __syncthreads(); // prev-iter LDS reads complete before overwrite
        size_t gA0 = (size_t)(m0 + arow) * K + k0 + acol;
        size_t gA1 = (size_t)(m0 + 64 + arow) * K + k0 + acol;
        size_t gB0 = (size_t)(n0 + arow) * K + k0 + acol;
        size_t gB1 = (size_t)(n0 + 64 + arow) * K + k0 + acol;
        gload16(Ah + gA0, (char*)sAh + lo0);
        gload16(Ah + gA1, (char*)sAh + lo1);
        gload16(Al + gA0, (char*)sAl + lo0);
        gload16(Al + gA1, (char*)sAl + lo1);
        gload16(Bh + gB0, (char*)sBh + lo0);
        gload16(Bh + gB1, (char*)sBh + lo1);
        gload16(Bl + gB0, (char*)sBl + lo0);
        gload16(Bl + gB1, (char*)sBl + lo1);
        asm volatile("s_waitcnt vmcnt(0)" ::: "memory");
        __syncthreads();

        bf16x8 fah[4], fal[4], fbh[4], fbl[4];
#pragma unroll
        for (int i = 0; i < 4; ++i) {
            int ra = (wr * 64 + i * 16 + l15) * 32 + l4 * 8;
            int rb = (wc * 64 + i * 16 + l15) * 32 + l4 * 8;
            fah[i] = *reinterpret_cast<const bf16x8*>(sAh + ra);
            fal[i] = *reinterpret_cast<const bf16x8*>(sAl + ra);
            fbh[i] = *reinterpret_cast<const bf16x8*>(sBh + rb);
            fbl[i] = *reinterpret_cast<const bf16x8*>(sBl + rb);
        }
#pragma unroll
        for (int i = 0; i < 4; ++i)
#pragma unroll
            for (int j = 0; j < 4; ++j) {
                acc[i][j] = __builtin_amdgcn_mfma_f32_16x16x32_bf16(fal[i], fbh[j], acc[i][j], 0, 0, 0);
                acc[i][j] = __builtin_amdgcn_mfma_f32_16x16x32_bf16(fah[i], fbl[j], acc[i][j], 0, 0, 0);
                acc[i][j] = __builtin_amdgcn_mfma_f32_16x16x32_bf16(fah[i], fbh[j], acc[i][j], 0, 0, 0);
            }
    }

    // epilogue: C row = 4*(lane>>4)+reg, col = lane&15 (verified m89/m91 layout)
#pragma unroll
    for (int j = 0; j < 4; ++j) {
        int col = n0 + wc * 64 + j * 16 + l15;
        float bv = bias ? bias[col] : 0.0f;
#pragma unroll
        for (int i = 0; i < 4; ++i) {
            int rbase = m0 + wr * 64 + i * 16 + l4 * 4;
#pragma unroll
            for (int r = 0; r < 4; ++r) {
                float v = acc[i][j][r] + bv;
                if (RELU) v = fmaxf(v, 0.0f);
                v *= scale;
                size_t idx = (size_t)(rbase + r) * N + col;
                if (SPLIT) {
                    bf16 h = __float2bfloat16(v);
                    Ch[idx] = h;
                    Cl[idx] = __float2bfloat16(v - __bfloat162float(h));
                } else {
                    Cf[idx] = v;
                }
            }
        }
    }
}

extern "C" void kernel_launch(void* const* d_in, const int* in_sizes, int n_in,
                              void* d_out, int out_size, void* d_ws, size_t ws_size,
                              hipStream_t stream) {
    const float* query = (const float*)d_in[0];
    const float* key   = (const float*)d_in[1];
    const float* q1_w  = (const float*)d_in[2];
    const float* q1_b  = (const float*)d_in[3];
    const float* q2_w  = (const float*)d_in[4];
    const float* q2_b  = (const float*)d_in[5];
    const float* k1_w  = (const float*)d_in[6];
    const float* k1_b  = (const float*)d_in[7];
    const float* k2_w  = (const float*)d_in[8];
    const float* k2_b  = (const float*)d_in[9];
    float* out = (float*)d_out;

    char* ws = (char*)d_ws;
    size_t o = 0;
    bf16* xcat_h = (bf16*)(ws + o); o += (size_t)NK * 768 * 2; // 50.3 MB
    bf16* xcat_l = (bf16*)(ws + o); o += (size_t)NK * 768 * 2; // 50.3 MB
    // x_key pair overlays the xcat region (xcat dead after gemm(a))
    bf16* xk_h = xcat_h;
    bf16* xk_l = xcat_l;
    bf16* qh   = (bf16*)(ws + o); o += (size_t)MQ * DIM * 2;
    bf16* ql   = (bf16*)(ws + o); o += (size_t)MQ * DIM * 2;
    bf16* q1h  = (bf16*)(ws + o); o += 65536 * 2;
    bf16* q1l  = (bf16*)(ws + o); o += 65536 * 2;
    bf16* q2h  = (bf16*)(ws + o); o += 65536 * 2;
    bf16* q2l  = (bf16*)(ws + o); o += 65536 * 2;
    bf16* k1h  = (bf16*)(ws + o); o += 196608 * 2;
    bf16* k1l  = (bf16*)(ws + o); o += 196608 * 2;
    bf16* k2h  = (bf16*)(ws + o); o += 65536 * 2;
    bf16* k2l  = (bf16*)(ws + o); o += 65536 * 2;
    bf16* hq1h = (bf16*)(ws + o); o += (size_t)MQ * DIM * 2;
    bf16* hq1l = (bf16*)(ws + o); o += (size_t)MQ * DIM * 2;
    bf16* xqh  = (bf16*)(ws + o); o += (size_t)MQ * DIM * 2;
    bf16* xql  = (bf16*)(ws + o); o += (size_t)MQ * DIM * 2;
    float* cmax = (float*)(ws + o); o += (size_t)NCHUNK * DIM * 4;
    float* cbef = (float*)(ws + o); o += (size_t)NCHUNK * DIM * 4;
    float* caft = (float*)(ws + o); o += (size_t)NCHUNK * DIM * 4;
    // h1 pair parked in d_out (dead before final GEMM overwrites it)
    bf16* h1h = (bf16*)d_out;
    bf16* h1l = h1h + (size_t)NK * DIM;

    convert_kernel<<<2560, 256, 0, stream>>>(query, q1_w, q2_w, k1_w, k2_w,
                                             qh, ql, q1h, q1l, q2h, q2l, k1h, k1l, k2h, k2l);
    chunkmax_kernel<<<NCHUNK, 256, 0, stream>>>(key, cmax);
    chunkscan_kernel<<<1, 256, 0, stream>>>(cmax, cbef, caft);
    scanwrite_kernel<<<NCHUNK, 256, 0, stream>>>(key, cbef, caft, xcat_h, xcat_l);

    // h1 = relu(xcat @ k1_w^T + k1_b)    M=32768 N=256 K=768
    gemm_bs<true, true><<<dim3(2, NK / 128), 256, 0, stream>>>(
        xcat_h, xcat_l, k1h, k1l, k1_b, nullptr, h1h, h1l, NK, DIM, 768, 1.0f);
    // x_key = h1 @ k2_w^T + k2_b         M=32768 N=256 K=256
    gemm_bs<false, true><<<dim3(2, NK / 128), 256, 0, stream>>>(
        h1h, h1l, k2h, k2l, k2_b, nullptr, xk_h, xk_l, NK, DIM, DIM, 1.0f);
    // query path
    gemm_bs<true, true><<<dim3(2, MQ / 128), 256, 0, stream>>>(
        qh, ql, q1h, q1l, q1_b, nullptr, hq1h, hq1l, MQ, DIM, DIM, 1.0f);
    gemm_bs<false, true><<<dim3(2, MQ / 128), 256, 0, stream>>>(
        hq1h, hq1l, q2h, q2l, q2_b, nullptr, xqh, xql, MQ, DIM, DIM, 1.0f);
    // out = (x_query @ x_key^T) / 16     M=1024 N=32768 K=256
    gemm_bs<false, false><<<dim3(NK / 128, MQ / 128), 256, 0, stream>>>(
        xqh, xql, xk_h, xk_l, nullptr, out, nullptr, nullptr, MQ, NK, DIM, 0.0625f);
}

// Round 3
// 245.625 us; speedup vs baseline: 2.2671x; 1.0669x over previous
//
#include <hip/hip_runtime.h>
#include <hip/hip_bf16.h>

// CrossAttentionSequencePool — split-bf16 MFMA, depth-2 counted-vmcnt pipeline.
//  scan (fp32) -> xcat hi/lo bf16 [32768,768]
//  gemm_bs<768,relu,split>: h1 = relu(xcat @ k1_w^T + b)   (h1 pair in d_out)
//  gemm_bs<256,.,split>:    x_key = h1 @ k2_w^T + b        (overlays dead xcat)
//  query path same, final: out = (x_query @ x_key^T)/16 fp32.
// GEMM: 128x128 tile, BK=32, 4 waves, 3 MFMA products (ah*bh + ah*bl + al*bh),
// LDS double-buffered, raw s_barrier + counted vmcnt(8) so prefetch loads stay
// in flight across barriers (T3/T4). LDS atom-col XOR-swizzled by (row>>1)&3 on
// BOTH global-source and ds_read side (rule #21) -> 2-way banks (free).

#define NK 32768
#define DIM 256
#define MQ 1024
#define CHUNK 64
#define NCHUNK (NK / CHUNK)

typedef __hip_bfloat16 bf16;
typedef short bf16x8 __attribute__((ext_vector_type(8)));
typedef float f32x4 __attribute__((ext_vector_type(4)));

__device__ __forceinline__ void gload16(const void* g, void* l) {
    __builtin_amdgcn_global_load_lds(
        (const __attribute__((address_space(1))) unsigned int*)g,
        (__attribute__((address_space(3))) unsigned int*)l, 16, 0, 0);
}

__device__ __forceinline__ void st2(bf16* __restrict__ xh, bf16* __restrict__ xl,
                                    size_t idx, float v0, float v1) {
    bf16 h0 = __float2bfloat16(v0), h1 = __float2bfloat16(v1);
    __hip_bfloat162 vh, vl;
    vh.x = h0; vh.y = h1;
    vl.x = __float2bfloat16(v0 - __bfloat162float(h0));
    vl.y = __float2bfloat16(v1 - __bfloat162float(h1));
    *reinterpret_cast<__hip_bfloat162*>(xh + idx) = vh;
    *reinterpret_cast<__hip_bfloat162*>(xl + idx) = vl;
}

// ---------------- scan ----------------
__global__ __launch_bounds__(256) void chunkmax_kernel(const float* __restrict__ key,
                                                       float* __restrict__ cmax) {
    int col = threadIdx.x, c = blockIdx.x;
    const float* p = key + (size_t)c * CHUNK * DIM + col;
    float m = -INFINITY;
#pragma unroll 8
    for (int r = 0; r < CHUNK; ++r) m = fmaxf(m, p[(size_t)r * DIM]);
    cmax[c * DIM + col] = m;
}

__global__ __launch_bounds__(256) void chunkscan_kernel(const float* __restrict__ cmax,
                                                        float* __restrict__ cbef,
                                                        float* __restrict__ caft) {
    int col = threadIdx.x;
    float run = -INFINITY;
    for (int c = 0; c < NCHUNK; ++c) {
        cbef[c * DIM + col] = run;
        run = fmaxf(run, cmax[c * DIM + col]);
    }
    run = -INFINITY;
    for (int c = NCHUNK - 1; c >= 0; --c) {
        caft[c * DIM + col] = run;
        run = fmaxf(run, cmax[c * DIM + col]);
    }
}

// xcat hi/lo: row -> [key | x_before | x_after]; 128 threads x 2 cols each.
__global__ __launch_bounds__(128) void scanwrite_kernel(const float* __restrict__ key,
                                                        const float* __restrict__ cbef,
                                                        const float* __restrict__ caft,
                                                        bf16* __restrict__ xh,
                                                        bf16* __restrict__ xl) {
    __shared__ float2 sk[CHUNK][DIM / 2];
    int t = threadIdx.x, c = blockIdx.x;
    int c0 = t * 2;
    float r0 = cbef[c * DIM + c0], r1 = cbef[c * DIM + c0 + 1];
    for (int r = 0; r < CHUNK; ++r) {
        int gr = c * CHUNK + r;
        float2 kv = *reinterpret_cast<const float2*>(key + (size_t)gr * DIM + c0);
        sk[r][t] = kv;
        size_t base = (size_t)gr * (3 * DIM) + c0;
        st2(xh, xl, base, kv.x, kv.y);
        st2(xh, xl, base + DIM, gr == 0 ? 0.f : r0, gr == 0 ? 0.f : r1);
        r0 = fmaxf(r0, kv.x);
        r1 = fmaxf(r1, kv.y);
    }
    r0 = caft[c * DIM + c0];
    r1 = caft[c * DIM + c0 + 1];
    for (int r = CHUNK - 1; r >= 0; --r) {
        int gr = c * CHUNK + r;
        float2 kv = sk[r][t];
        size_t base = (size_t)gr * (3 * DIM) + c0;
        st2(xh, xl, base + 2 * DIM, gr == NK - 1 ? 0.f : r0, gr == NK - 1 ? 0.f : r1);
        r0 = fmaxf(r0, kv.x);
        r1 = fmaxf(r1, kv.y);
    }
}

// ---------------- converts (weights + query) ----------------
__global__ __launch_bounds__(256) void convert_kernel(
    const float* __restrict__ q, const float* __restrict__ q1w, const float* __restrict__ q2w,
    const float* __restrict__ k1w, const float* __restrict__ k2w,
    bf16* qh, bf16* ql, bf16* q1h, bf16* q1l, bf16* q2h, bf16* q2l,
    bf16* k1h, bf16* k1l, bf16* k2h, bf16* k2l) {
    int i = blockIdx.x * 256 + threadIdx.x;
    const float* src; bf16 *dh, *dl; int off;
    if (i < 262144)      { src = q;   dh = qh;  dl = ql;  off = i; }
    else if (i < 327680) { src = q1w; dh = q1h; dl = q1l; off = i - 262144; }
    else if (i < 393216) { src = q2w; dh = q2h; dl = q2l; off = i - 327680; }
    else if (i < 589824) { src = k1w; dh = k1h; dl = k1l; off = i - 393216; }
    else                 { src = k2w; dh = k2h; dl = k2l; off = i - 589824; }
    float v = src[off];
    bf16 h = __float2bfloat16(v);
    dh[off] = h;
    dl[off] = __float2bfloat16(v - __bfloat162float(h));
}

// ---------------- split-bf16 MFMA GEMM (NT), pipelined ----------------
template <int K, bool RELU, bool SPLIT>
__global__ __launch_bounds__(256, 2) void gemm_bs(
    const bf16* __restrict__ Ah, const bf16* __restrict__ Al,
    const bf16* __restrict__ Bh, const bf16* __restrict__ Bl,
    const float* __restrict__ bias,
    float* __restrict__ Cf, bf16* __restrict__ Ch, bf16* __restrict__ Cl,
    int M, int N, float scale) {
    // [buf][hi/lo][128*32] bf16 panels, 8KB each -> 64KB total
    __shared__ __align__(16) bf16 sA[2][2][128 * 32];
    __shared__ __align__(16) bf16 sB[2][2][128 * 32];
    const int t = threadIdx.x;
    const int lane = t & 63, wid = t >> 6;
    const int m0 = blockIdx.y * 128, n0 = blockIdx.x * 128;
    const int wr = wid >> 1, wc = wid & 1;
    const int l15 = lane & 15, l4 = lane >> 4;
    const int T = K / 32;

    // staging geometry: panel = 8 chunks of 1KB; wave handles chunks wid, wid+4.
    // chunk c, lane l -> LDS atom c*64+l, i.e. row 16c+(l>>2), atom-col (l&3).
    // Pre-swizzled GLOBAL col so LDS(row, a) = global(row, a ^ ((row>>1)&3)).
    const int r16 = lane >> 2;
    const int cSw = ((lane & 3) ^ ((lane >> 3) & 3)) * 8; // swizzled col offset (elems)
    const int row0 = wid * 16 + r16;
    const int row1 = row0 + 64;
    const unsigned off0 = (unsigned)(wid * 1024);
    const unsigned off1 = off0 + 4096;

    f32x4 acc[4][4];
#pragma unroll
    for (int i = 0; i < 4; ++i)
#pragma unroll
        for (int j = 0; j < 4; ++j) {
            acc[i][j][0] = 0.f; acc[i][j][1] = 0.f; acc[i][j][2] = 0.f; acc[i][j][3] = 0.f;
        }

    auto stage = [&](int tt, int bb) {
        const int kc = tt * 32 + cSw;
        gload16(Ah + (size_t)(m0 + row0) * K + kc, (char*)&sA[bb][0][0] + off0);
        gload16(Ah + (size_t)(m0 + row1) * K + kc, (char*)&sA[bb][0][0] + off1);
        gload16(Al + (size_t)(m0 + row0) * K + kc, (char*)&sA[bb][1][0] + off0);
        gload16(Al + (size_t)(m0 + row1) * K + kc, (char*)&sA[bb][1][0] + off1);
        gload16(Bh + (size_t)(n0 + row0) * K + kc, (char*)&sB[bb][0][0] + off0);
        gload16(Bh + (size_t)(n0 + row1) * K + kc, (char*)&sB[bb][0][0] + off1);
        gload16(Bl + (size_t)(n0 + row0) * K + kc, (char*)&sB[bb][1][0] + off0);
        gload16(Bl + (size_t)(n0 + row1) * K + kc, (char*)&sB[bb][1][0] + off1);
    };

    // prologue: tiles 0,1 staged; wait tile 0 (8 of tile 1 stay in flight)
    stage(0, 0);
    stage(1, 1);
    asm volatile("s_waitcnt vmcnt(8)" ::: "memory");
    __builtin_amdgcn_s_barrier();

    for (int tt = 0; tt < T; ++tt) {
        const int b = tt & 1;
        bf16x8 fah[4], fal[4], fbh[4], fbl[4];
#pragma unroll
        for (int i = 0; i < 4; ++i) {
            const int sw = (l4 ^ ((l15 >> 1) & 3)) * 8; // read-side swizzle
            const int ra = (wr * 64 + i * 16 + l15) * 32 + sw;
            const int rb = (wc * 64 + i * 16 + l15) * 32 + sw;
            fah[i] = *reinterpret_cast<const bf16x8*>(&sA[b][0][ra]);
            fal[i] = *reinterpret_cast<const bf16x8*>(&sA[b][1][ra]);
            fbh[i] = *reinterpret_cast<const bf16x8*>(&sB[b][0][rb]);
            fbl[i] = *reinterpret_cast<const bf16x8*>(&sB[b][1][rb]);
        }
        asm volatile("s_waitcnt lgkmcnt(0)" ::: "memory"); // all reads of buf b done
        __builtin_amdgcn_s_barrier();                      // ... in every wave
        if (tt + 2 < T) stage(tt + 2, b);                  // overwrite buf b
        __builtin_amdgcn_s_setprio(1);
#pragma unroll
        for (int i = 0; i < 4; ++i)
#pragma unroll
            for (int j = 0; j < 4; ++j) {
                acc[i][j] = __builtin_amdgcn_mfma_f32_16x16x32_bf16(fal[i], fbh[j], acc[i][j], 0, 0, 0);
                acc[i][j] = __builtin_amdgcn_mfma_f32_16x16x32_bf16(fah[i], fbl[j], acc[i][j], 0, 0, 0);
                acc[i][j] = __builtin_amdgcn_mfma_f32_16x16x32_bf16(fah[i], fbh[j], acc[i][j], 0, 0, 0);
            }
        __builtin_amdgcn_s_setprio(0);
        if (tt + 2 < T) {
            asm volatile("s_waitcnt vmcnt(8)" ::: "memory"); // tile tt+1 landed; tt+2 in flight
        } else {
            asm volatile("s_waitcnt vmcnt(0)" ::: "memory"); // tail drain
        }
        __builtin_amdgcn_s_barrier();
    }

    // epilogue: C row = 4*(lane>>4)+reg, col = lane&15 (m89/m91 layout)
#pragma unroll
    for (int j = 0; j < 4; ++j) {
        int col = n0 + wc * 64 + j * 16 + l15;
        float bv = bias ? bias[col] : 0.0f;
#pragma unroll
        for (int i = 0; i < 4; ++i) {
            int rbase = m0 + wr * 64 + i * 16 + l4 * 4;
#pragma unroll
            for (int r = 0; r < 4; ++r) {
                float v = acc[i][j][r] + bv;
                if (RELU) v = fmaxf(v, 0.0f);
                v *= scale;
                size_t idx = (size_t)(rbase + r) * N + col;
                if (SPLIT) {
                    bf16 h = __float2bfloat16(v);
                    Ch[idx] = h;
                    Cl[idx] = __float2bfloat16(v - __bfloat162float(h));
                } else {
                    Cf[idx] = v;
                }
            }
        }
    }
}

extern "C" void kernel_launch(void* const* d_in, const int* in_sizes, int n_in,
                              void* d_out, int out_size, void* d_ws, size_t ws_size,
                              hipStream_t stream) {
    const float* query = (const float*)d_in[0];
    const float* key   = (const float*)d_in[1];
    const float* q1_w  = (const float*)d_in[2];
    const float* q1_b  = (const float*)d_in[3];
    const float* q2_w  = (const float*)d_in[4];
    const float* q2_b  = (const float*)d_in[5];
    const float* k1_w  = (const float*)d_in[6];
    const float* k1_b  = (const float*)d_in[7];
    const float* k2_w  = (const float*)d_in[8];
    const float* k2_b  = (const float*)d_in[9];
    float* out = (float*)d_out;

    char* ws = (char*)d_ws;
    size_t o = 0;
    bf16* xcat_h = (bf16*)(ws + o); o += (size_t)NK * 768 * 2;
    bf16* xcat_l = (bf16*)(ws + o); o += (size_t)NK * 768 * 2;
    bf16* xk_h = xcat_h; // overlays dead xcat after gemm(a)
    bf16* xk_l = xcat_l;
    bf16* qh   = (bf16*)(ws + o); o += (size_t)MQ * DIM * 2;
    bf16* ql   = (bf16*)(ws + o); o += (size_t)MQ * DIM * 2;
    bf16* q1h  = (bf16*)(ws + o); o += 65536 * 2;
    bf16* q1l  = (bf16*)(ws + o); o += 65536 * 2;
    bf16* q2h  = (bf16*)(ws + o); o += 65536 * 2;
    bf16* q2l  = (bf16*)(ws + o); o += 65536 * 2;
    bf16* k1h  = (bf16*)(ws + o); o += 196608 * 2;
    bf16* k1l  = (bf16*)(ws + o); o += 196608 * 2;
    bf16* k2h  = (bf16*)(ws + o); o += 65536 * 2;
    bf16* k2l  = (bf16*)(ws + o); o += 65536 * 2;
    bf16* hq1h = (bf16*)(ws + o); o += (size_t)MQ * DIM * 2;
    bf16* hq1l = (bf16*)(ws + o); o += (size_t)MQ * DIM * 2;
    bf16* xqh  = (bf16*)(ws + o); o += (size_t)MQ * DIM * 2;
    bf16* xql  = (bf16*)(ws + o); o += (size_t)MQ * DIM * 2;
    float* cmax = (float*)(ws + o); o += (size_t)NCHUNK * DIM * 4;
    float* cbef = (float*)(ws + o); o += (size_t)NCHUNK * DIM * 4;
    float* caft = (float*)(ws + o); o += (size_t)NCHUNK * DIM * 4;
    bf16* h1h = (bf16*)d_out; // parked in d_out, dead before final GEMM
    bf16* h1l = h1h + (size_t)NK * DIM;

    convert_kernel<<<2560, 256, 0, stream>>>(query, q1_w, q2_w, k1_w, k2_w,
                                             qh, ql, q1h, q1l, q2h, q2l, k1h, k1l, k2h, k2l);
    chunkmax_kernel<<<NCHUNK, 256, 0, stream>>>(key, cmax);
    chunkscan_kernel<<<1, 256, 0, stream>>>(cmax, cbef, caft);
    scanwrite_kernel<<<NCHUNK, 128, 0, stream>>>(key, cbef, caft, xcat_h, xcat_l);

    // h1 = relu(xcat @ k1_w^T + k1_b)    M=32768 N=256 K=768
    gemm_bs<768, true, true><<<dim3(2, NK / 128), 256, 0, stream>>>(
        xcat_h, xcat_l, k1h, k1l, k1_b, nullptr, h1h, h1l, NK, DIM, 1.0f);
    // x_key = h1 @ k2_w^T + k2_b         M=32768 N=256 K=256
    gemm_bs<256, false, true><<<dim3(2, NK / 128), 256, 0, stream>>>(
        h1h, h1l, k2h, k2l, k2_b, nullptr, xk_h, xk_l, NK, DIM, 1.0f);
    // query path
    gemm_bs<256, true, true><<<dim3(2, MQ / 128), 256, 0, stream>>>(
        qh, ql, q1h, q1l, q1_b, nullptr, hq1h, hq1l, MQ, DIM, 1.0f);
    gemm_bs<256, false, true><<<dim3(2, MQ / 128), 256, 0, stream>>>(
        hq1h, hq1l, q2h, q2l, q2_b, nullptr, xqh, xql, MQ, DIM, 1.0f);
    // out = (x_query @ x_key^T) / 16     M=1024 N=32768 K=256
    gemm_bs<256, false, false><<<dim3(NK / 128, MQ / 128), 256, 0, stream>>>(
        xqh, xql, xk_h, xk_l, nullptr, out, nullptr, nullptr, MQ, NK, 0.0625f);
}

// Round 4
// 145.951 us; speedup vs baseline: 3.8154x; 1.6829x over previous
//
#include <hip/hip_runtime.h>
#include <hip/hip_bf16.h>

// CrossAttentionSequencePool — plain fp16 single-product MFMA pipeline.
//  scan (fp32) -> xcat f16 [32768,768]
//  gemm<768,relu>: h1 = relu(xcat @ k1_w^T + b)      f16
//  gemm<256>:      x_key = h1 @ k2_w^T + b           f16
//  query path same (tiny), final: out = (xq @ xk^T)/16 -> fp32
// fp16 (11-bit mantissa) single product: total added error ~6e-4 vs 0.0144
// threshold (vs 3x-product split-bf16 at 2x traffic + 3x MFMA in r2/r3).
// GEMM: 128x128 tile, BK=32, 4 waves, depth-2 counted-vmcnt pipeline (r3
// structure, vmcnt(4)), atom-col XOR swizzle both sides (r3: 0 conflicts),
// XCD-aware block swizzle (T1).

#define NK 32768
#define DIM 256
#define MQ 1024
#define CHUNK 64
#define NCHUNK (NK / CHUNK)

typedef _Float16 f16;
typedef _Float16 f16x8 __attribute__((ext_vector_type(8)));
typedef float f32x4 __attribute__((ext_vector_type(4)));

__device__ __forceinline__ void gload16(const void* g, void* l) {
    __builtin_amdgcn_global_load_lds(
        (const __attribute__((address_space(1))) unsigned int*)g,
        (__attribute__((address_space(3))) unsigned int*)l, 16, 0, 0);
}

// ---------------- scan ----------------
__global__ __launch_bounds__(256) void chunkmax_kernel(const float* __restrict__ key,
                                                       float* __restrict__ cmax) {
    int col = threadIdx.x, c = blockIdx.x;
    const float* p = key + (size_t)c * CHUNK * DIM + col;
    float m = -INFINITY;
#pragma unroll 8
    for (int r = 0; r < CHUNK; ++r) m = fmaxf(m, p[(size_t)r * DIM]);
    cmax[c * DIM + col] = m;
}

// block 0: forward exclusive scan; block 1: backward
__global__ __launch_bounds__(256) void chunkscan_kernel(const float* __restrict__ cmax,
                                                        float* __restrict__ cbef,
                                                        float* __restrict__ caft) {
    int col = threadIdx.x;
    float run = -INFINITY;
    if (blockIdx.x == 0) {
#pragma unroll 8
        for (int c = 0; c < NCHUNK; ++c) {
            cbef[c * DIM + col] = run;
            run = fmaxf(run, cmax[c * DIM + col]);
        }
    } else {
#pragma unroll 8
        for (int c = NCHUNK - 1; c >= 0; --c) {
            caft[c * DIM + col] = run;
            run = fmaxf(run, cmax[c * DIM + col]);
        }
    }
}

// xcat f16: row -> [key | x_before | x_after]
__global__ __launch_bounds__(256) void scanwrite_kernel(const float* __restrict__ key,
                                                        const float* __restrict__ cbef,
                                                        const float* __restrict__ caft,
                                                        f16* __restrict__ x) {
    __shared__ float sk[CHUNK][DIM];
    int col = threadIdx.x, c = blockIdx.x;
    float run = cbef[c * DIM + col]; // -inf for c==0
    for (int r = 0; r < CHUNK; ++r) {
        int gr = c * CHUNK + r;
        float kv = key[(size_t)gr * DIM + col];
        sk[r][col] = kv;
        size_t base = (size_t)gr * (3 * DIM) + col;
        x[base] = (f16)kv;
        x[base + DIM] = (f16)(gr == 0 ? 0.0f : run);
        run = fmaxf(run, kv);
    }
    run = caft[c * DIM + col]; // -inf for last chunk
    for (int r = CHUNK - 1; r >= 0; --r) {
        int gr = c * CHUNK + r;
        size_t base = (size_t)(c * CHUNK + r) * (3 * DIM) + col;
        x[base + 2 * DIM] = (f16)(gr == NK - 1 ? 0.0f : run);
        run = fmaxf(run, sk[r][col]);
    }
}

// ---------------- convert (query + weights) to f16 ----------------
__global__ __launch_bounds__(256) void convert_kernel(
    const float* __restrict__ q, const float* __restrict__ q1w, const float* __restrict__ q2w,
    const float* __restrict__ k1w, const float* __restrict__ k2w,
    f16* qf, f16* q1f, f16* q2f, f16* k1f, f16* k2f) {
    int i = blockIdx.x * 256 + threadIdx.x;
    const float* src; f16* dst; int off;
    if (i < 262144)      { src = q;   dst = qf;  off = i; }
    else if (i < 327680) { src = q1w; dst = q1f; off = i - 262144; }
    else if (i < 393216) { src = q2w; dst = q2f; off = i - 327680; }
    else if (i < 589824) { src = k1w; dst = k1f; off = i - 393216; }
    else                 { src = k2w; dst = k2f; off = i - 589824; }
    dst[off] = (f16)src[off];
}

// ---------------- fp16 MFMA GEMM (NT), depth-2 pipeline ----------------
// SWZ: 0 = none; 1 = m-grouped XCD (grid 512: (2,256)); 2 = n-grouped (grid 2048: (256,8))
template <int K, int SWZ, bool RELU, bool OUTF16>
__global__ __launch_bounds__(256, 4) void gemm_f16(
    const f16* __restrict__ A, const f16* __restrict__ B,
    const float* __restrict__ bias,
    float* __restrict__ Cf, f16* __restrict__ Ch,
    int N, float scale) {
    __shared__ __align__(16) f16 sA[2][128 * 32];
    __shared__ __align__(16) f16 sB[2][128 * 32];
    const int t = threadIdx.x;
    const int lane = t & 63, wid = t >> 6;

    int mt, nt;
    if (SWZ == 1) { // each XCD: 32 consecutive m-tiles x 2 n-tiles
        int bid = blockIdx.y * gridDim.x + blockIdx.x;
        int xcd = bid & 7, i = bid >> 3;
        mt = xcd * 32 + (i >> 1);
        nt = i & 1;
    } else if (SWZ == 2) { // each XCD: 32 consecutive n-tiles x all m-tiles
        int bid = blockIdx.y * gridDim.x + blockIdx.x;
        int xcd = bid & 7, i = bid >> 3;
        nt = xcd * 32 + (i & 31);
        mt = i >> 5;
    } else {
        mt = blockIdx.y;
        nt = blockIdx.x;
    }
    const int m0 = mt * 128, n0 = nt * 128;
    const int wr = wid >> 1, wc = wid & 1;
    const int l15 = lane & 15, l4 = lane >> 4;
    constexpr int T = K / 32;

    // staging: panel 8KB = 8 chunks of 1KB; wave wid stages chunks wid, wid+4.
    // LDS dest is wave-uniform base + lane*16; global col pre-swizzled so that
    // LDS(row, atom a) = global(row, a ^ ((row>>1)&3)).   (r3-verified, 0 conflicts)
    const int row0 = wid * 16 + (lane >> 2);
    const int row1 = row0 + 64;
    const int cSw = ((lane & 3) ^ ((lane >> 3) & 3)) * 8;
    const unsigned off0 = (unsigned)(wid * 1024);
    const unsigned off1 = off0 + 4096;

    f32x4 acc[4][4];
#pragma unroll
    for (int i = 0; i < 4; ++i)
#pragma unroll
        for (int j = 0; j < 4; ++j) {
            acc[i][j][0] = 0.f; acc[i][j][1] = 0.f; acc[i][j][2] = 0.f; acc[i][j][3] = 0.f;
        }

    auto stage = [&](int tt, int bb) { // 4 loads
        const int kc = tt * 32 + cSw;
        gload16(A + (size_t)(m0 + row0) * K + kc, (char*)&sA[bb][0] + off0);
        gload16(A + (size_t)(m0 + row1) * K + kc, (char*)&sA[bb][0] + off1);
        gload16(B + (size_t)(n0 + row0) * K + kc, (char*)&sB[bb][0] + off0);
        gload16(B + (size_t)(n0 + row1) * K + kc, (char*)&sB[bb][0] + off1);
    };

    stage(0, 0);
    stage(1, 1);
    asm volatile("s_waitcnt vmcnt(4)" ::: "memory"); // tile 0 landed, tile 1 in flight
    __builtin_amdgcn_s_barrier();

    for (int tt = 0; tt < T; ++tt) {
        const int b = tt & 1;
        f16x8 fa[4], fb[4];
#pragma unroll
        for (int i = 0; i < 4; ++i) {
            const int sw = (l4 ^ ((l15 >> 1) & 3)) * 8; // read-side swizzle
            fa[i] = *reinterpret_cast<const f16x8*>(&sA[b][(wr * 64 + i * 16 + l15) * 32 + sw]);
            fb[i] = *reinterpret_cast<const f16x8*>(&sB[b][(wc * 64 + i * 16 + l15) * 32 + sw]);
        }
        asm volatile("s_waitcnt lgkmcnt(0)" ::: "memory"); // frags in regs
        __builtin_amdgcn_s_barrier();                      // all waves done with buf b
        if (tt + 2 < T) stage(tt + 2, b);                  // overwrite buf b
        __builtin_amdgcn_s_setprio(1);
#pragma unroll
        for (int i = 0; i < 4; ++i)
#pragma unroll
            for (int j = 0; j < 4; ++j)
                acc[i][j] = __builtin_amdgcn_mfma_f32_16x16x32_f16(fa[i], fb[j], acc[i][j], 0, 0, 0);
        __builtin_amdgcn_s_setprio(0);
        if (tt + 2 < T) {
            asm volatile("s_waitcnt vmcnt(4)" ::: "memory"); // tile tt+1 landed
        } else {
            asm volatile("s_waitcnt vmcnt(0)" ::: "memory"); // tail drain
        }
        __builtin_amdgcn_s_barrier();
    }

    // epilogue: C row = 4*(lane>>4)+reg, col = lane&15 (m89/m91 layout)
#pragma unroll
    for (int j = 0; j < 4; ++j) {
        int col = n0 + wc * 64 + j * 16 + l15;
        float bv = bias ? bias[col] : 0.0f;
#pragma unroll
        for (int i = 0; i < 4; ++i) {
            int rbase = m0 + wr * 64 + i * 16 + l4 * 4;
#pragma unroll
            for (int r = 0; r < 4; ++r) {
                float v = acc[i][j][r] + bv;
                if (RELU) v = fmaxf(v, 0.0f);
                v *= scale;
                size_t idx = (size_t)(rbase + r) * N + col;
                if (OUTF16) Ch[idx] = (f16)v;
                else Cf[idx] = v;
            }
        }
    }
}

extern "C" void kernel_launch(void* const* d_in, const int* in_sizes, int n_in,
                              void* d_out, int out_size, void* d_ws, size_t ws_size,
                              hipStream_t stream) {
    const float* query = (const float*)d_in[0];
    const float* key   = (const float*)d_in[1];
    const float* q1_w  = (const float*)d_in[2];
    const float* q1_b  = (const float*)d_in[3];
    const float* q2_w  = (const float*)d_in[4];
    const float* q2_b  = (const float*)d_in[5];
    const float* k1_w  = (const float*)d_in[6];
    const float* k1_b  = (const float*)d_in[7];
    const float* k2_w  = (const float*)d_in[8];
    const float* k2_b  = (const float*)d_in[9];
    float* out = (float*)d_out;

    char* ws = (char*)d_ws;
    size_t o = 0;
    f16* xcat = (f16*)(ws + o); o += (size_t)NK * 768 * 2;   // 48 MB
    f16* h1   = (f16*)(ws + o); o += (size_t)NK * DIM * 2;   // 16 MB
    f16* xk   = (f16*)(ws + o); o += (size_t)NK * DIM * 2;   // 16 MB
    f16* qf   = (f16*)(ws + o); o += (size_t)MQ * DIM * 2;
    f16* q1f  = (f16*)(ws + o); o += 65536 * 2;
    f16* q2f  = (f16*)(ws + o); o += 65536 * 2;
    f16* k1f  = (f16*)(ws + o); o += 196608 * 2;
    f16* k2f  = (f16*)(ws + o); o += 65536 * 2;
    f16* hq1  = (f16*)(ws + o); o += (size_t)MQ * DIM * 2;
    f16* xq   = (f16*)(ws + o); o += (size_t)MQ * DIM * 2;
    float* cmax = (float*)(ws + o); o += (size_t)NCHUNK * DIM * 4;
    float* cbef = (float*)(ws + o); o += (size_t)NCHUNK * DIM * 4;
    float* caft = (float*)(ws + o); o += (size_t)NCHUNK * DIM * 4;

    convert_kernel<<<2560, 256, 0, stream>>>(query, q1_w, q2_w, k1_w, k2_w,
                                             qf, q1f, q2f, k1f, k2f);
    chunkmax_kernel<<<NCHUNK, 256, 0, stream>>>(key, cmax);
    chunkscan_kernel<<<2, 256, 0, stream>>>(cmax, cbef, caft);
    scanwrite_kernel<<<NCHUNK, 256, 0, stream>>>(key, cbef, caft, xcat);

    // h1 = relu(xcat @ k1_w^T + k1_b)    M=32768 N=256 K=768
    gemm_f16<768, 1, true, true><<<dim3(2, NK / 128), 256, 0, stream>>>(
        xcat, k1f, k1_b, nullptr, h1, DIM, 1.0f);
    // x_key = h1 @ k2_w^T + k2_b         M=32768 N=256 K=256
    gemm_f16<256, 1, false, true><<<dim3(2, NK / 128), 256, 0, stream>>>(
        h1, k2f, k2_b, nullptr, xk, DIM, 1.0f);
    // query path (tiny)
    gemm_f16<256, 0, true, true><<<dim3(2, MQ / 128), 256, 0, stream>>>(
        qf, q1f, q1_b, nullptr, hq1, DIM, 1.0f);
    gemm_f16<256, 0, false, true><<<dim3(2, MQ / 128), 256, 0, stream>>>(
        hq1, q2f, q2_b, nullptr, xq, DIM, 1.0f);
    // out = (x_query @ x_key^T) / 16     M=1024 N=32768 K=256
    gemm_f16<256, 2, false, false><<<dim3(NK / 128, MQ / 128), 256, 0, stream>>>(
        xq, xk, nullptr, out, nullptr, NK, 0.0625f);
}

// Round 5
// 126.725 us; speedup vs baseline: 4.3942x; 1.1517x over previous
//
#include <hip/hip_runtime.h>
#include <hip/hip_bf16.h>

// CrossAttentionSequencePool — fp16 MFMA, gemm_b algebraically eliminated.
//  out = (xq @ xk^T)/16,  xk = h1@k2^T + k2_b
//      = (xq@k2) @ h1^T /16 + ((xq.k2_b)/16) 1^T  =  yq @ h1^T * (1/16) + c[m]
// Pipeline:
//  scan (3-level) -> xcat f16 [32768,768]
//  gemm<768,relu>: h1 = relu(xcat @ k1_w^T + k1_b)       (the only big-M MLP GEMM)
//  qmlp (16 blocks): hq1 -> xq -> yq = xq@k2, c = (xq.k2_b)/16  (3 phases in-LDS)
//  final gemm: out = yq @ h1^T * 1/16 + c (row bias)
// GEMM: r4-proven 128x128/BK=32 depth-2 counted-vmcnt pipeline, both-side
// atom-XOR swizzle (0 bank conflicts), XCD swizzle.

#define NK 32768
#define DIM 256
#define MQ 1024
#define CHUNK 64
#define NCHUNK (NK / CHUNK) // 512
#define NSEG 16
#define SEGCH (NCHUNK / NSEG) // 32

typedef _Float16 f16;
typedef _Float16 f16x8 __attribute__((ext_vector_type(8)));
typedef float f32x4 __attribute__((ext_vector_type(4)));

__device__ __forceinline__ void gload16(const void* g, void* l) {
    __builtin_amdgcn_global_load_lds(
        (const __attribute__((address_space(1))) unsigned int*)g,
        (__attribute__((address_space(3))) unsigned int*)l, 16, 0, 0);
}

// ---------------- scan (3-level) ----------------
__global__ __launch_bounds__(256) void chunkmax_kernel(const float* __restrict__ key,
                                                       float* __restrict__ cmax) {
    int col = threadIdx.x, c = blockIdx.x;
    const float* p = key + (size_t)c * CHUNK * DIM + col;
    float m = -INFINITY;
#pragma unroll 8
    for (int r = 0; r < CHUNK; ++r) m = fmaxf(m, p[(size_t)r * DIM]);
    cmax[c * DIM + col] = m;
}

// 32 blocks: 0..15 forward segs, 16..31 backward segs. Within-seg exclusive
// partials into pbef/paft; seg totals into stot[dir][seg].
__global__ __launch_bounds__(256) void segscan_kernel(const float* __restrict__ cmax,
                                                      float* __restrict__ pbef,
                                                      float* __restrict__ paft,
                                                      float* __restrict__ stot) {
    int col = threadIdx.x, b = blockIdx.x;
    int dir = b >> 4, s = b & 15;
    float run = -INFINITY;
    if (dir == 0) {
#pragma unroll 8
        for (int i = 0; i < SEGCH; ++i) {
            int c = s * SEGCH + i;
            pbef[c * DIM + col] = run;
            run = fmaxf(run, cmax[c * DIM + col]);
        }
        stot[s * DIM + col] = run;
    } else {
#pragma unroll 8
        for (int i = SEGCH - 1; i >= 0; --i) {
            int c = s * SEGCH + i;
            paft[c * DIM + col] = run;
            run = fmaxf(run, cmax[c * DIM + col]);
        }
        stot[(NSEG + s) * DIM + col] = run;
    }
}

// exclusive scan over 16 segment totals, both directions
__global__ __launch_bounds__(256) void segpref_kernel(const float* __restrict__ stot,
                                                      float* __restrict__ spref) {
    int col = threadIdx.x;
    float run = -INFINITY;
#pragma unroll
    for (int s = 0; s < NSEG; ++s) {
        spref[s * DIM + col] = run;
        run = fmaxf(run, stot[s * DIM + col]);
    }
    run = -INFINITY;
#pragma unroll
    for (int s = NSEG - 1; s >= 0; --s) {
        spref[(NSEG + s) * DIM + col] = run;
        run = fmaxf(run, stot[(NSEG + s) * DIM + col]);
    }
}

// xcat f16 row -> [key | x_before | x_after]; 128 thr x 2 cols, packed stores.
__global__ __launch_bounds__(128) void scanwrite_kernel(const float* __restrict__ key,
                                                        const float* __restrict__ pbef,
                                                        const float* __restrict__ paft,
                                                        const float* __restrict__ spref,
                                                        f16* __restrict__ x) {
    __shared__ float2 sk[CHUNK][DIM / 2];
    int t = threadIdx.x, c = blockIdx.x, s = c >> 5;
    int c0 = t * 2;
    float r0 = fmaxf(pbef[c * DIM + c0], spref[s * DIM + c0]);
    float r1 = fmaxf(pbef[c * DIM + c0 + 1], spref[s * DIM + c0 + 1]);
    for (int r = 0; r < CHUNK; ++r) {
        int gr = c * CHUNK + r;
        float2 kv = *reinterpret_cast<const float2*>(key + (size_t)gr * DIM + c0);
        sk[r][t] = kv;
        size_t base = (size_t)gr * (3 * DIM) + c0;
        f16 k0 = (f16)kv.x, k1 = (f16)kv.y;
        *reinterpret_cast<__attribute__((ext_vector_type(2))) _Float16*>(x + base) =
            (__attribute__((ext_vector_type(2))) _Float16){k0, k1};
        f16 b0 = (f16)(gr == 0 ? 0.f : r0), b1 = (f16)(gr == 0 ? 0.f : r1);
        *reinterpret_cast<__attribute__((ext_vector_type(2))) _Float16*>(x + base + DIM) =
            (__attribute__((ext_vector_type(2))) _Float16){b0, b1};
        r0 = fmaxf(r0, kv.x);
        r1 = fmaxf(r1, kv.y);
    }
    r0 = fmaxf(paft[c * DIM + c0], spref[(NSEG + s) * DIM + c0]);
    r1 = fmaxf(paft[c * DIM + c0 + 1], spref[(NSEG + s) * DIM + c0 + 1]);
    for (int r = CHUNK - 1; r >= 0; --r) {
        int gr = c * CHUNK + r;
        float2 kv = sk[r][t];
        size_t base = (size_t)gr * (3 * DIM) + c0;
        f16 a0 = (f16)(gr == NK - 1 ? 0.f : r0), a1 = (f16)(gr == NK - 1 ? 0.f : r1);
        *reinterpret_cast<__attribute__((ext_vector_type(2))) _Float16*>(x + base + 2 * DIM) =
            (__attribute__((ext_vector_type(2))) _Float16){a0, a1};
        r0 = fmaxf(r0, kv.x);
        r1 = fmaxf(r1, kv.y);
    }
}

// ---------------- convert: query + weights to f16 (k2 transposed) ----------------
__global__ __launch_bounds__(256) void convert_kernel(
    const float* __restrict__ q, const float* __restrict__ q1w, const float* __restrict__ q2w,
    const float* __restrict__ k1w, const float* __restrict__ k2w,
    f16* qf, f16* q1f, f16* q2f, f16* k1f, f16* k2t) {
    int i = blockIdx.x * 256 + threadIdx.x;
    if (i < 262144)      { qf[i] = (f16)q[i]; }
    else if (i < 327680) { int o = i - 262144; q1f[o] = (f16)q1w[o]; }
    else if (i < 393216) { int o = i - 327680; q2f[o] = (f16)q2w[o]; }
    else if (i < 589824) { int o = i - 393216; k1f[o] = (f16)k1w[o]; }
    else { // k2t[n][k] = k2[k][n]
        int o = i - 589824;
        int k = o >> 8, n = o & 255;
        k2t[n * 256 + k] = (f16)k2w[o];
    }
}

// ---------------- fused query MLP: hq1 -> xq -> yq, c ----------------
// 16 blocks x 256 thr (4 waves), 64-row tile, wave = col quadrant.
// h-tile parked in 32KB panel-swizzled LDS between phases.
__global__ __launch_bounds__(256) void qmlp_kernel(
    const f16* __restrict__ qf, const f16* __restrict__ q1f,
    const f16* __restrict__ q2f, const f16* __restrict__ k2t,
    const float* __restrict__ q1_b, const float* __restrict__ q2_b,
    const float* __restrict__ k2_b,
    f16* __restrict__ yq, float* __restrict__ cvec) {
    __shared__ __align__(16) f16 hbuf[8 * 64 * 32]; // 8 k-panels of [64 rows][32 k]
    __shared__ __align__(16) f16 sA[64 * 32];
    __shared__ __align__(16) f16 sB[256 * 32];
    __shared__ float cpart[64][4];
    const int t = threadIdx.x, lane = t & 63, wid = t >> 6;
    const int m0 = blockIdx.x * 64;
    const int l15 = lane & 15, l4 = lane >> 4;
    const int r16 = lane >> 2;
    const int cSw = ((lane & 3) ^ ((lane >> 3) & 3)) * 8; // pre-swizzled global atom
    const int sw = (l4 ^ ((l15 >> 1) & 3)) * 8;           // read-side swizzle

    auto hb_addr = [&](int row, int col) {
        return (col >> 5) * 2048 + row * 32 +
               ((((col & 31) >> 3) ^ ((row >> 1) & 3)) << 3) + (col & 7);
    };
    auto stageB = [&](const f16* B, int tt) {
#pragma unroll
        for (int cc = 0; cc < 4; ++cc) {
            int row = wid * 64 + cc * 16 + r16;
            gload16(B + (size_t)row * 256 + tt * 32 + cSw, (char*)sB + (wid * 4 + cc) * 1024);
        }
    };

    f32x4 acc[4][4];
#define ZACC                                                        \
    _Pragma("unroll") for (int i = 0; i < 4; ++i)                   \
        _Pragma("unroll") for (int j = 0; j < 4; ++j) {             \
            acc[i][j][0] = 0.f; acc[i][j][1] = 0.f;                 \
            acc[i][j][2] = 0.f; acc[i][j][3] = 0.f;                 \
        }
#define MFMA16                                                      \
    _Pragma("unroll") for (int i = 0; i < 4; ++i)                   \
        _Pragma("unroll") for (int j = 0; j < 4; ++j)               \
            acc[i][j] = __builtin_amdgcn_mfma_f32_16x16x32_f16(fa[i], fb[j], acc[i][j], 0, 0, 0);

    // ---- phase 1: h = relu(q @ q1^T + q1_b) ----
    ZACC
    for (int tt = 0; tt < 8; ++tt) {
        __syncthreads();
        gload16(qf + (size_t)(m0 + wid * 16 + r16) * 256 + tt * 32 + cSw,
                (char*)sA + wid * 1024);
        stageB(q1f, tt);
        asm volatile("s_waitcnt vmcnt(0)" ::: "memory");
        __syncthreads();
        f16x8 fa[4], fb[4];
#pragma unroll
        for (int i = 0; i < 4; ++i)
            fa[i] = *reinterpret_cast<const f16x8*>(&sA[(i * 16 + l15) * 32 + sw]);
#pragma unroll
        for (int j = 0; j < 4; ++j)
            fb[j] = *reinterpret_cast<const f16x8*>(&sB[(wid * 64 + j * 16 + l15) * 32 + sw]);
        MFMA16
    }
#pragma unroll
    for (int j = 0; j < 4; ++j) {
        int col = wid * 64 + j * 16 + l15;
        float bv = q1_b[col];
#pragma unroll
        for (int i = 0; i < 4; ++i)
#pragma unroll
            for (int r = 0; r < 4; ++r)
                hbuf[hb_addr(i * 16 + l4 * 4 + r, col)] = (f16)fmaxf(acc[i][j][r] + bv, 0.f);
    }

    // ---- phase 2: xq = h @ q2^T + q2_b ----
    ZACC
    for (int tt = 0; tt < 8; ++tt) {
        __syncthreads(); // also makes epilogue-1 hbuf writes visible (tt==0)
        stageB(q2f, tt);
        asm volatile("s_waitcnt vmcnt(0)" ::: "memory");
        __syncthreads();
        f16x8 fa[4], fb[4];
#pragma unroll
        for (int i = 0; i < 4; ++i)
            fa[i] = *reinterpret_cast<const f16x8*>(&hbuf[tt * 2048 + (i * 16 + l15) * 32 + sw]);
#pragma unroll
        for (int j = 0; j < 4; ++j)
            fb[j] = *reinterpret_cast<const f16x8*>(&sB[(wid * 64 + j * 16 + l15) * 32 + sw]);
        MFMA16
    }
    __syncthreads(); // all waves' hbuf reads done before overwrite
#pragma unroll
    for (int j = 0; j < 4; ++j) {
        int col = wid * 64 + j * 16 + l15;
        float bv = q2_b[col];
#pragma unroll
        for (int i = 0; i < 4; ++i)
#pragma unroll
            for (int r = 0; r < 4; ++r)
                hbuf[hb_addr(i * 16 + l4 * 4 + r, col)] = (f16)(acc[i][j][r] + bv);
    }
    __syncthreads();

    // ---- c[m] = (xq . k2_b) / 16 ----
    {
        int row = t & 63, qtr = t >> 6;
        float s = 0.f;
        for (int k = qtr * 64; k < qtr * 64 + 64; ++k)
            s += (float)hbuf[hb_addr(row, k)] * k2_b[k];
        cpart[row][qtr] = s;
    }
    __syncthreads();
    if (t < 64)
        cvec[m0 + t] = (cpart[t][0] + cpart[t][1] + cpart[t][2] + cpart[t][3]) * 0.0625f;

    // ---- phase 3: yq = xq @ k2  (B = k2t) ----
    ZACC
    for (int tt = 0; tt < 8; ++tt) {
        __syncthreads();
        stageB(k2t, tt);
        asm volatile("s_waitcnt vmcnt(0)" ::: "memory");
        __syncthreads();
        f16x8 fa[4], fb[4];
#pragma unroll
        for (int i = 0; i < 4; ++i)
            fa[i] = *reinterpret_cast<const f16x8*>(&hbuf[tt * 2048 + (i * 16 + l15) * 32 + sw]);
#pragma unroll
        for (int j = 0; j < 4; ++j)
            fb[j] = *reinterpret_cast<const f16x8*>(&sB[(wid * 64 + j * 16 + l15) * 32 + sw]);
        MFMA16
    }
#pragma unroll
    for (int j = 0; j < 4; ++j) {
        int col = wid * 64 + j * 16 + l15;
#pragma unroll
        for (int i = 0; i < 4; ++i)
#pragma unroll
            for (int r = 0; r < 4; ++r)
                yq[(size_t)(m0 + i * 16 + l4 * 4 + r) * 256 + col] = (f16)acc[i][j][r];
    }
#undef ZACC
#undef MFMA16
}

// ---------------- fp16 MFMA GEMM (NT), depth-2 pipeline ----------------
// SWZ: 0 none; 1 m-grouped XCD; 2 n-grouped XCD. Optional col-bias and row-bias.
template <int K, int SWZ, bool RELU, bool OUTF16>
__global__ __launch_bounds__(256, 4) void gemm_f16(
    const f16* __restrict__ A, const f16* __restrict__ B,
    const float* __restrict__ bias, const float* __restrict__ rowbias,
    float* __restrict__ Cf, f16* __restrict__ Ch,
    int N, float scale) {
    __shared__ __align__(16) f16 sA[2][128 * 32];
    __shared__ __align__(16) f16 sB[2][128 * 32];
    const int t = threadIdx.x;
    const int lane = t & 63, wid = t >> 6;

    int mt, nt;
    if (SWZ == 1) {
        int bid = blockIdx.y * gridDim.x + blockIdx.x;
        int xcd = bid & 7, i = bid >> 3;
        mt = xcd * 32 + (i >> 1);
        nt = i & 1;
    } else if (SWZ == 2) {
        int bid = blockIdx.y * gridDim.x + blockIdx.x;
        int xcd = bid & 7, i = bid >> 3;
        nt = xcd * 32 + (i & 31);
        mt = i >> 5;
    } else {
        mt = blockIdx.y;
        nt = blockIdx.x;
    }
    const int m0 = mt * 128, n0 = nt * 128;
    const int wr = wid >> 1, wc = wid & 1;
    const int l15 = lane & 15, l4 = lane >> 4;
    constexpr int T = K / 32;

    const int row0 = wid * 16 + (lane >> 2);
    const int row1 = row0 + 64;
    const int cSw = ((lane & 3) ^ ((lane >> 3) & 3)) * 8;
    const unsigned off0 = (unsigned)(wid * 1024);
    const unsigned off1 = off0 + 4096;

    f32x4 acc[4][4];
#pragma unroll
    for (int i = 0; i < 4; ++i)
#pragma unroll
        for (int j = 0; j < 4; ++j) {
            acc[i][j][0] = 0.f; acc[i][j][1] = 0.f; acc[i][j][2] = 0.f; acc[i][j][3] = 0.f;
        }

    auto stage = [&](int tt, int bb) {
        const int kc = tt * 32 + cSw;
        gload16(A + (size_t)(m0 + row0) * K + kc, (char*)&sA[bb][0] + off0);
        gload16(A + (size_t)(m0 + row1) * K + kc, (char*)&sA[bb][0] + off1);
        gload16(B + (size_t)(n0 + row0) * K + kc, (char*)&sB[bb][0] + off0);
        gload16(B + (size_t)(n0 + row1) * K + kc, (char*)&sB[bb][0] + off1);
    };

    stage(0, 0);
    stage(1, 1);
    asm volatile("s_waitcnt vmcnt(4)" ::: "memory");
    __builtin_amdgcn_s_barrier();

    for (int tt = 0; tt < T; ++tt) {
        const int b = tt & 1;
        f16x8 fa[4], fb[4];
#pragma unroll
        for (int i = 0; i < 4; ++i) {
            const int sw = (l4 ^ ((l15 >> 1) & 3)) * 8;
            fa[i] = *reinterpret_cast<const f16x8*>(&sA[b][(wr * 64 + i * 16 + l15) * 32 + sw]);
            fb[i] = *reinterpret_cast<const f16x8*>(&sB[b][(wc * 64 + i * 16 + l15) * 32 + sw]);
        }
        asm volatile("s_waitcnt lgkmcnt(0)" ::: "memory");
        __builtin_amdgcn_s_barrier();
        if (tt + 2 < T) stage(tt + 2, b);
        __builtin_amdgcn_s_setprio(1);
#pragma unroll
        for (int i = 0; i < 4; ++i)
#pragma unroll
            for (int j = 0; j < 4; ++j)
                acc[i][j] = __builtin_amdgcn_mfma_f32_16x16x32_f16(fa[i], fb[j], acc[i][j], 0, 0, 0);
        __builtin_amdgcn_s_setprio(0);
        if (tt + 2 < T) {
            asm volatile("s_waitcnt vmcnt(4)" ::: "memory");
        } else {
            asm volatile("s_waitcnt vmcnt(0)" ::: "memory");
        }
        __builtin_amdgcn_s_barrier();
    }

#pragma unroll
    for (int j = 0; j < 4; ++j) {
        int col = n0 + wc * 64 + j * 16 + l15;
        float bv = bias ? bias[col] : 0.0f;
#pragma unroll
        for (int i = 0; i < 4; ++i) {
            int rbase = m0 + wr * 64 + i * 16 + l4 * 4;
#pragma unroll
            for (int r = 0; r < 4; ++r) {
                float v = acc[i][j][r] + bv;
                if (RELU) v = fmaxf(v, 0.0f);
                v *= scale;
                if (rowbias) v += rowbias[rbase + r];
                size_t idx = (size_t)(rbase + r) * N + col;
                if (OUTF16) Ch[idx] = (f16)v;
                else Cf[idx] = v;
            }
        }
    }
}

extern "C" void kernel_launch(void* const* d_in, const int* in_sizes, int n_in,
                              void* d_out, int out_size, void* d_ws, size_t ws_size,
                              hipStream_t stream) {
    const float* query = (const float*)d_in[0];
    const float* key   = (const float*)d_in[1];
    const float* q1_w  = (const float*)d_in[2];
    const float* q1_b  = (const float*)d_in[3];
    const float* q2_w  = (const float*)d_in[4];
    const float* q2_b  = (const float*)d_in[5];
    const float* k1_w  = (const float*)d_in[6];
    const float* k1_b  = (const float*)d_in[7];
    const float* k2_w  = (const float*)d_in[8];
    const float* k2_b  = (const float*)d_in[9];
    float* out = (float*)d_out;

    char* ws = (char*)d_ws;
    size_t o = 0;
    f16* xcat = (f16*)(ws + o); o += (size_t)NK * 768 * 2;   // 48 MB
    f16* h1   = (f16*)(ws + o); o += (size_t)NK * DIM * 2;   // 16 MB
    f16* qf   = (f16*)(ws + o); o += (size_t)MQ * DIM * 2;
    f16* q1f  = (f16*)(ws + o); o += 65536 * 2;
    f16* q2f  = (f16*)(ws + o); o += 65536 * 2;
    f16* k1f  = (f16*)(ws + o); o += 196608 * 2;
    f16* k2t  = (f16*)(ws + o); o += 65536 * 2;
    f16* yq   = (f16*)(ws + o); o += (size_t)MQ * DIM * 2;
    float* cvec = (float*)(ws + o); o += MQ * 4;
    float* cmax = (float*)(ws + o); o += (size_t)NCHUNK * DIM * 4;
    float* pbef = (float*)(ws + o); o += (size_t)NCHUNK * DIM * 4;
    float* paft = (float*)(ws + o); o += (size_t)NCHUNK * DIM * 4;
    float* stot = (float*)(ws + o); o += 2 * NSEG * DIM * 4;
    float* spref = (float*)(ws + o); o += 2 * NSEG * DIM * 4;

    convert_kernel<<<2560, 256, 0, stream>>>(query, q1_w, q2_w, k1_w, k2_w,
                                             qf, q1f, q2f, k1f, k2t);
    chunkmax_kernel<<<NCHUNK, 256, 0, stream>>>(key, cmax);
    segscan_kernel<<<2 * NSEG, 256, 0, stream>>>(cmax, pbef, paft, stot);
    segpref_kernel<<<1, 256, 0, stream>>>(stot, spref);
    scanwrite_kernel<<<NCHUNK, 128, 0, stream>>>(key, pbef, paft, spref, xcat);
    qmlp_kernel<<<MQ / 64, 256, 0, stream>>>(qf, q1f, q2f, k2t,
                                             q1_b, q2_b, k2_b, yq, cvec);

    // h1 = relu(xcat @ k1_w^T + k1_b)    M=32768 N=256 K=768
    gemm_f16<768, 1, true, true><<<dim3(2, NK / 128), 256, 0, stream>>>(
        xcat, k1f, k1_b, nullptr, nullptr, h1, DIM, 1.0f);
    // out = yq @ h1^T / 16 + c[m]        M=1024 N=32768 K=256
    gemm_f16<256, 2, false, false><<<dim3(NK / 128, MQ / 128), 256, 0, stream>>>(
        yq, h1, nullptr, cvec, out, nullptr, NK, 0.0625f);
}